// Round 1
// baseline (113.378 us; speedup 1.0000x reference)
//
#include <hip/hip_runtime.h>

// KDA delta-rule state update, B=H=32, K=V=256, fp32.
// out[k,v] = g[k]*S[k,v] + beta*key[k]*(val[v] - kt[v]),
// kt[v] = sum_k key[k]*g[k]*S[k,v].
// One 1024-thread block per (b,h) tile; tile held in registers between
// the kt-reduction and the output pass -> single HBM read of state.

#define KD 256
#define VD 256

__global__ __launch_bounds__(1024, 4)
void kda_update_kernel(const float* __restrict__ state,
                       const float* __restrict__ keys,
                       const float* __restrict__ values,
                       const float* __restrict__ gates,
                       const float* __restrict__ beta,
                       float* __restrict__ out)
{
    const int bh = blockIdx.x;
    const size_t tile_off = (size_t)bh * (KD * VD);
    const float4* __restrict__ S4 = (const float4*)(state + tile_off);
    float4* __restrict__ O4 = (float4*)(out + tile_off);

    __shared__ float  s_g[KD];        // alpha
    __shared__ float  s_w[KD];        // alpha * key
    __shared__ float  s_c[KD];        // beta * key
    __shared__ float4 s_part[16][64]; // per-wave kt partials (16 KiB)
    __shared__ float4 s_kt[64];       // final kt (1 KiB)

    const int t = threadIdx.x;
    const int a = t >> 6;   // wave id 0..15
    const int b = t & 63;   // lane

    if (t < KD) {
        const float g = gates[bh * KD + t];
        const float k = keys[bh * KD + t];
        s_g[t] = g;
        s_w[t] = g * k;
        s_c[t] = beta[bh] * k;
    }

    // Load the tile: thread t owns float4 indices t + 1024*j.
    // -> row k = a + 16*j, float4-column b. Wave reads 1 KiB contiguous.
    float4 s[16];
#pragma unroll
    for (int j = 0; j < 16; ++j) {
        s[j] = S4[t + 1024 * j];
    }

    __syncthreads();  // s_w/s_g/s_c ready (loads above overlap the barrier)

    // Phase 1: per-thread partial of kt over the 16 rows this thread touches.
    float4 p = make_float4(0.f, 0.f, 0.f, 0.f);
#pragma unroll
    for (int j = 0; j < 16; ++j) {
        const float w = s_w[a + 16 * j];
        p.x = fmaf(w, s[j].x, p.x);
        p.y = fmaf(w, s[j].y, p.y);
        p.z = fmaf(w, s[j].z, p.z);
        p.w = fmaf(w, s[j].w, p.w);
    }
    s_part[a][b] = p;
    __syncthreads();

    // Cross-wave reduce: 64 threads, each sums 16 partials for its column group.
    if (t < 64) {
        float4 acc = s_part[0][t];
#pragma unroll
        for (int i = 1; i < 16; ++i) {
            const float4 q = s_part[i][t];
            acc.x += q.x; acc.y += q.y; acc.z += q.z; acc.w += q.w;
        }
        s_kt[t] = acc;
    }
    __syncthreads();

    // Phase 2: output from registers (no HBM re-read).
    const float4 kt = s_kt[b];
    const float4 vv = ((const float4*)(values + (size_t)bh * VD))[b];
    const float4 d = make_float4(vv.x - kt.x, vv.y - kt.y, vv.z - kt.z, vv.w - kt.w);

#pragma unroll
    for (int j = 0; j < 16; ++j) {
        const int k = a + 16 * j;
        const float g = s_g[k];
        const float c = s_c[k];
        float4 o;
        o.x = fmaf(g, s[j].x, c * d.x);
        o.y = fmaf(g, s[j].y, c * d.y);
        o.z = fmaf(g, s[j].z, c * d.z);
        o.w = fmaf(g, s[j].w, c * d.w);
        O4[t + 1024 * j] = o;
    }
}

extern "C" void kernel_launch(void* const* d_in, const int* in_sizes, int n_in,
                              void* d_out, int out_size, void* d_ws, size_t ws_size,
                              hipStream_t stream) {
    const float* state  = (const float*)d_in[0];
    const float* keys   = (const float*)d_in[1];
    const float* values = (const float*)d_in[2];
    const float* gates  = (const float*)d_in[3];
    const float* beta   = (const float*)d_in[4];
    float* out = (float*)d_out;

    dim3 grid(32 * 32);   // one block per (b,h)
    dim3 block(1024);
    hipLaunchKernelGGL(kda_update_kernel, grid, block, 0, stream,
                       state, keys, values, gates, beta, out);
}

// Round 3
// 105.672 us; speedup vs baseline: 1.0729x; 1.0729x over previous
//
#include <hip/hip_runtime.h>

// KDA delta-rule state update, B=H=32, K=V=256, fp32.
// out[k,v] = g[k]*S[k,v] + beta*key[k]*(val[v] - kt[v]),
// kt[v] = sum_k key[k]*g[k]*S[k,v]   (column-independent in v).
//
// V is split into 4 slices of 64 -> block = 256 threads owning a 256x64
// sub-tile in registers (16 f32x4/thread). 4 blocks/CU resident so one
// block's reduce/store phase overlaps another's load phase.
// f32x4 = clang ext_vector (not HIP_vector_type) so the nontemporal
// builtins accept its pointer.

#define KD 256
#define VD 256
#define SW 16   // f32x4 columns per slice (64 floats)

typedef float f32x4 __attribute__((ext_vector_type(4)));

__global__ __launch_bounds__(256, 4)
void kda_update_kernel(const float* __restrict__ state,
                       const float* __restrict__ keys,
                       const float* __restrict__ values,
                       const float* __restrict__ gates,
                       const float* __restrict__ beta,
                       float* __restrict__ out)
{
    const int bh    = blockIdx.x >> 2;   // (b,h) tile
    const int slice = blockIdx.x & 3;    // v-slice within tile
    const size_t tile_off = (size_t)bh * (KD * VD);
    const f32x4* __restrict__ S4 = (const f32x4*)(state + tile_off);
    f32x4* __restrict__ O4 = (f32x4*)(out + tile_off);

    __shared__ float s_g[KD];           // alpha
    __shared__ float s_w[KD];           // alpha * key
    __shared__ float s_c[KD];           // beta * key
    __shared__ f32x4 s_part[16][SW];    // per-rowgroup kt partials (4 KiB)
    __shared__ f32x4 s_kt[SW];          // final kt for this slice

    const int t  = threadIdx.x;
    const int c  = t & (SW - 1);        // f32x4 col within slice
    const int r0 = t >> 4;              // row group 0..15
    const int c0 = slice * SW;          // slice's f32x4 col offset

    // Per-row scalars (256 threads, 256 rows: one each).
    {
        const float g = gates[bh * KD + t];
        const float k = keys[bh * KD + t];
        s_g[t] = g;
        s_w[t] = g * k;
        s_c[t] = beta[bh] * k;
    }

    // Load sub-tile: thread (r0,c) owns rows k = r0 + 16j, f32x4-col c0+c.
    // Each 16-lane group reads 256 B contiguous -> fully coalesced.
    f32x4 s[16];
#pragma unroll
    for (int j = 0; j < 16; ++j) {
        s[j] = __builtin_nontemporal_load(&S4[(size_t)(r0 + 16 * j) * (VD / 4) + c0 + c]);
    }

    __syncthreads();  // scalars ready

    // Phase 1: per-thread partial kt over this thread's 16 rows.
    f32x4 p = (f32x4)(0.f);
#pragma unroll
    for (int j = 0; j < 16; ++j) {
        const float w = s_w[r0 + 16 * j];
        p.x = fmaf(w, s[j].x, p.x);
        p.y = fmaf(w, s[j].y, p.y);
        p.z = fmaf(w, s[j].z, p.z);
        p.w = fmaf(w, s[j].w, p.w);
    }
    s_part[r0][c] = p;
    __syncthreads();

    // Cross-rowgroup reduce: 16 threads, one per f32x4 col (tiny).
    if (t < SW) {
        f32x4 acc = s_part[0][t];
#pragma unroll
        for (int i = 1; i < 16; ++i) {
            const f32x4 q = s_part[i][t];
            acc.x += q.x; acc.y += q.y; acc.z += q.z; acc.w += q.w;
        }
        s_kt[t] = acc;
    }
    __syncthreads();

    // Phase 2: output from registers (no HBM re-read).
    const f32x4 kt = s_kt[c];
    const f32x4 vv = ((const f32x4*)(values + (size_t)bh * VD))[c0 + c];
    f32x4 d;
    d.x = vv.x - kt.x; d.y = vv.y - kt.y; d.z = vv.z - kt.z; d.w = vv.w - kt.w;

#pragma unroll
    for (int j = 0; j < 16; ++j) {
        const int k = r0 + 16 * j;
        const float g  = s_g[k];
        const float cb = s_c[k];
        f32x4 o;
        o.x = fmaf(g, s[j].x, cb * d.x);
        o.y = fmaf(g, s[j].y, cb * d.y);
        o.z = fmaf(g, s[j].z, cb * d.z);
        o.w = fmaf(g, s[j].w, cb * d.w);
        __builtin_nontemporal_store(o, &O4[(size_t)k * (VD / 4) + c0 + c]);
    }
}

extern "C" void kernel_launch(void* const* d_in, const int* in_sizes, int n_in,
                              void* d_out, int out_size, void* d_ws, size_t ws_size,
                              hipStream_t stream) {
    const float* state  = (const float*)d_in[0];
    const float* keys   = (const float*)d_in[1];
    const float* values = (const float*)d_in[2];
    const float* gates  = (const float*)d_in[3];
    const float* beta   = (const float*)d_in[4];
    float* out = (float*)d_out;

    dim3 grid(32 * 32 * 4);  // (b,h) x 4 v-slices
    dim3 block(256);
    hipLaunchKernelGGL(kda_update_kernel, grid, block, 0, stream,
                       state, keys, values, gates, beta, out);
}